// Round 2
// baseline (142.950 us; speedup 1.0000x reference)
//
#include <hip/hip_runtime.h>

// hidden = tanh(x @ (Wi+Wh)^T + (bi+bh)); h_last = hidden[:, T-1, :]
// x:(16,4096,256) fp32 -> GEMM M=65536, N=256, K=256, fp32 out.
// Barrier-free structure: each block caches its 128-col half of
// W = bf16(Wi+Wh) in 64KB LDS once (no prep kernel), then each wave streams
// A rows from global (fp32 -> bf16 in-register) with NO further barriers.
// 512 thr = 8 waves; wave = 32 rows x 128 cols (acc 2x8 MFMA tiles).
// Grid 512 = 2 blocks/CU, all co-resident.

using short8 = __attribute__((ext_vector_type(8))) short;
using f32x4  = __attribute__((ext_vector_type(4))) float;

constexpr int Tn = 4096, Cn = 256, Hn = 256;
constexpr int Mn = 16 * Tn; // 65536

// round-to-nearest-even fp32 -> bf16, two packed into one u32
__device__ inline unsigned pack2_bf16(float a, float b) {
  unsigned ua = __float_as_uint(a);
  unsigned ub = __float_as_uint(b);
  ua += 0x7fffu + ((ua >> 16) & 1u);
  ub += 0x7fffu + ((ub >> 16) & 1u);
  return (ua >> 16) | (ub & 0xffff0000u);
}

union u4s8 { uint4 u; short8 s; };

__global__ __launch_bounds__(512, 4) void fused_gemm_tanh(
    const float* __restrict__ x, const float* __restrict__ Wi,
    const float* __restrict__ bi, const float* __restrict__ Wh,
    const float* __restrict__ bh, float* __restrict__ out) {
  // 128 rows (n) x 256 (k) bf16, 16B-chunk XOR swizzle: chunk' = chunk^(row&7)
  __shared__ __align__(16) unsigned short Bsm[128 * 256]; // 64 KB exactly

  const int tid   = threadIdx.x;
  const int mb    = blockIdx.x >> 1;
  const int nb    = blockIdx.x & 1;
  const int mBase = mb * 256;
  const int nBase = nb * 128;

  // ---- stage W-half: 4096 16B-chunks, 8 per thread. Wi+Wh folded here.
#pragma unroll
  for (int i = 0; i < 8; i++) {
    int h = i * 512 + tid;   // 0..4095
    int r = h >> 5;          // local n-row 0..127
    int c = h & 31;          // 16B chunk in row (8 bf16 = 8 fp32 src)
    const float4* wi4 = (const float4*)(Wi + (size_t)(nBase + r) * Cn + c * 8);
    const float4* wh4 = (const float4*)(Wh + (size_t)(nBase + r) * Cn + c * 8);
    float4 a0 = wi4[0], a1 = wi4[1];
    float4 b0 = wh4[0], b1 = wh4[1];
    uint4 p;
    p.x = pack2_bf16(a0.x + b0.x, a0.y + b0.y);
    p.y = pack2_bf16(a0.z + b0.z, a0.w + b0.w);
    p.z = pack2_bf16(a1.x + b1.x, a1.y + b1.y);
    p.w = pack2_bf16(a1.z + b1.z, a1.w + b1.w);
    int pc = c ^ (r & 7);
    *(uint4*)&Bsm[(r << 8) + (pc << 3)] = p;
  }
  __syncthreads(); // the ONLY barrier

  const int wave = tid >> 6;      // 0..7 -> 32-row slice
  const int lane = tid & 63;
  const int rid  = lane & 15;     // row/col within 16x16 tile
  const int kgrp = lane >> 4;     // 0..3: k-group of 8
  const int rowBase = mBase + wave * 32;

  f32x4 acc[2][8];
#pragma unroll
  for (int im = 0; im < 2; im++)
#pragma unroll
    for (int in = 0; in < 8; in++) acc[im][in] = (f32x4)0.f;

  const float* a0p = x + (size_t)(rowBase + rid) * Cn + kgrp * 8;
  const float* a1p = a0p + (size_t)16 * Cn;

#pragma unroll 2
  for (int kc = 0; kc < 8; kc++) { // k = kc*32 .. +32
    short8 af[2];
    {
      const float4* p0 = (const float4*)(a0p + kc * 32);
      const float4* p1 = (const float4*)(a1p + kc * 32);
      float4 v0 = p0[0], v1 = p0[1];
      float4 w0 = p1[0], w1 = p1[1];
      u4s8 t0, t1;
      t0.u.x = pack2_bf16(v0.x, v0.y); t0.u.y = pack2_bf16(v0.z, v0.w);
      t0.u.z = pack2_bf16(v1.x, v1.y); t0.u.w = pack2_bf16(v1.z, v1.w);
      t1.u.x = pack2_bf16(w0.x, w0.y); t1.u.y = pack2_bf16(w0.z, w0.w);
      t1.u.z = pack2_bf16(w1.x, w1.y); t1.u.w = pack2_bf16(w1.z, w1.w);
      af[0] = t0.s; af[1] = t1.s;
    }
    short8 bf[8];
    const int cbase = (kc << 2) | kgrp;
#pragma unroll
    for (int in = 0; in < 8; in++) {
      int ln = in * 16 + rid;
      bf[in] = *(const short8*)&Bsm[(ln << 8) + ((cbase ^ (ln & 7)) << 3)];
    }
#pragma unroll
    for (int im = 0; im < 2; im++)
#pragma unroll
      for (int in = 0; in < 8; in++)
        acc[im][in] = __builtin_amdgcn_mfma_f32_16x16x32_bf16(
            af[im], bf[in], acc[im][in], 0, 0, 0);
  }

  // ---- epilogue: bias + tanh, write hidden (+ h_last rows)
#pragma unroll
  for (int in = 0; in < 8; in++) {
    int n = nBase + in * 16 + rid;
    float bias = bi[n] + bh[n]; // tiny, L2-resident
#pragma unroll
    for (int im = 0; im < 2; im++) {
      int mrow = rowBase + im * 16 + kgrp * 4;
#pragma unroll
      for (int r = 0; r < 4; r++) {
        int m = mrow + r;
        float v = acc[im][in][r] + bias;
        // tanh(v) = 1 - 2/(exp(2v)+1); overflow -> 1, underflow -> -1
        float t = 1.f - 2.f / (__expf(2.f * v) + 1.f);
        out[(size_t)m * Hn + n] = t;
        if ((m & (Tn - 1)) == (Tn - 1))
          out[(size_t)Mn * Hn + (size_t)(m >> 12) * Hn + n] = t;
      }
    }
  }
}

extern "C" void kernel_launch(void* const* d_in, const int* in_sizes, int n_in,
                              void* d_out, int out_size, void* d_ws,
                              size_t ws_size, hipStream_t stream) {
  (void)in_sizes; (void)n_in; (void)out_size; (void)d_ws; (void)ws_size;
  const float* x  = (const float*)d_in[0];
  const float* Wi = (const float*)d_in[1];
  const float* bi = (const float*)d_in[2];
  const float* Wh = (const float*)d_in[3];
  const float* bh = (const float*)d_in[4];
  float* out = (float*)d_out;

  // 512 blocks: (256 m-blocks of 256 rows) x (2 n-halves); all co-resident.
  fused_gemm_tanh<<<512, 512, 0, stream>>>(x, Wi, bi, Wh, bh, out);
}

// Round 3
// 135.859 us; speedup vs baseline: 1.0522x; 1.0522x over previous
//
#include <hip/hip_runtime.h>

// hidden = tanh(x @ (Wi+Wh)^T + (bi+bh)); h_last = hidden[:, -1, :]
// GEMM M=65536 N=256 K=256, fp32 in/out, bf16 MFMA inside.
// Memory-bound: ~134 MB min traffic -> ~21 us floor @ 6.3 TB/s.
// R3: latency fix. 256-thr blocks, launch_bounds(256,2) -> 256 VGPR/wave.
// Each wave prefetches its FULL K=256 A-slab (abuf[8][4] float4 = 128 VGPR,
// 16 KB/wave in flight) before computing -> MLP from registers, no barriers
// in the K-loop. W folded to bf16 once by a prep kernel; each block stages
// its 128-col half (64 KB LDS, XOR-swizzled 16B chunks).

using short8 = __attribute__((ext_vector_type(8))) short;
using f32x4  = __attribute__((ext_vector_type(4))) float;

constexpr int Tn = 4096, Cn = 256, Hn = 256;
constexpr int Mn = 16 * Tn; // 65536

// round-to-nearest-even fp32 -> bf16, two packed into one u32
__device__ inline unsigned pack2_bf16(float a, float b) {
  unsigned ua = __float_as_uint(a);
  unsigned ub = __float_as_uint(b);
  ua += 0x7fffu + ((ua >> 16) & 1u);
  ub += 0x7fffu + ((ub >> 16) & 1u);
  return (ua >> 16) | (ub & 0xffff0000u);
}

union u4s8 { uint4 u; short8 s; };

__global__ __launch_bounds__(256) void prep_kernel(
    const float* __restrict__ Wi, const float* __restrict__ bi,
    const float* __restrict__ Wh, const float* __restrict__ bh,
    unsigned short* __restrict__ Wc, float* __restrict__ bc) {
  int idx = blockIdx.x * 256 + threadIdx.x;
  float w = Wi[idx] + Wh[idx];
  unsigned u = __float_as_uint(w);
  u += 0x7fffu + ((u >> 16) & 1u);
  Wc[idx] = (unsigned short)(u >> 16);
  if (blockIdx.x == 0) bc[threadIdx.x] = bi[threadIdx.x] + bh[threadIdx.x];
}

// 256 thr = 4 waves. Block tile: 128 rows x 128 cols. Wave: 32 rows x 128 cols.
__global__ __launch_bounds__(256, 2) void gemm_tanh_kernel(
    const float* __restrict__ x, const unsigned short* __restrict__ Wc,
    const float* __restrict__ bc, float* __restrict__ out) {
  // 128 n-rows x 256 k bf16; 16B-chunk XOR swizzle: chunk' = chunk ^ (row&7)
  __shared__ __align__(16) unsigned short Bsm[128 * 256]; // 64 KB

  const int tid   = threadIdx.x;
  const int bid   = blockIdx.x;
  const int mb    = bid & 511;  // pair (mb, nb=0/1) lands on same XCD (512%8==0)
  const int nb    = bid >> 9;
  const int mBase = mb * 128;
  const int nBase = nb * 128;

  const int wave = tid >> 6;
  const int lane = tid & 63;
  const int rid  = lane & 15;  // row/col within 16x16 tile
  const int kgrp = lane >> 4;  // 0..3: k-group of 8
  const int rowBase = mBase + wave * 32;

  // ---- issue the ENTIRE A-slab for this wave first (32 x b128, 16 KB/wave)
  const float* a0p = x + (size_t)(rowBase + rid) * Cn + kgrp * 8;
  const float* a1p = a0p + (size_t)16 * Cn;
  float4 abuf[8][4];
#pragma unroll
  for (int kc = 0; kc < 8; kc++) {
    const float4* p0 = (const float4*)(a0p + kc * 32);
    const float4* p1 = (const float4*)(a1p + kc * 32);
    abuf[kc][0] = p0[0];
    abuf[kc][1] = p0[1];
    abuf[kc][2] = p1[0];
    abuf[kc][3] = p1[1];
  }

  // ---- stage W half (bf16, pre-folded): 4096 16B chunks, 16/thread
#pragma unroll
  for (int i = 0; i < 16; i++) {
    int h = i * 256 + tid; // 0..4095
    int r = h >> 5;        // local n-row 0..127
    int c = h & 31;        // 16B chunk
    uint4 v = *(const uint4*)(Wc + (size_t)(nBase + r) * Cn + c * 8);
    int pc = c ^ (r & 7);
    *(uint4*)&Bsm[(r << 8) + (pc << 3)] = v;
  }
  __syncthreads(); // the only barrier

  f32x4 acc[2][8];
#pragma unroll
  for (int im = 0; im < 2; im++)
#pragma unroll
    for (int in = 0; in < 8; in++) acc[im][in] = (f32x4)0.f;

#pragma unroll
  for (int kc = 0; kc < 8; kc++) {
    u4s8 t0, t1;
    t0.u.x = pack2_bf16(abuf[kc][0].x, abuf[kc][0].y);
    t0.u.y = pack2_bf16(abuf[kc][0].z, abuf[kc][0].w);
    t0.u.z = pack2_bf16(abuf[kc][1].x, abuf[kc][1].y);
    t0.u.w = pack2_bf16(abuf[kc][1].z, abuf[kc][1].w);
    t1.u.x = pack2_bf16(abuf[kc][2].x, abuf[kc][2].y);
    t1.u.y = pack2_bf16(abuf[kc][2].z, abuf[kc][2].w);
    t1.u.z = pack2_bf16(abuf[kc][3].x, abuf[kc][3].y);
    t1.u.w = pack2_bf16(abuf[kc][3].z, abuf[kc][3].w);
    short8 af[2] = {t0.s, t1.s};

    short8 bf[8];
    const int cbase = (kc << 2) | kgrp;
#pragma unroll
    for (int in = 0; in < 8; in++) {
      int ln = in * 16 + rid;
      bf[in] = *(const short8*)&Bsm[(ln << 8) + ((cbase ^ (ln & 7)) << 3)];
    }
#pragma unroll
    for (int im = 0; im < 2; im++)
#pragma unroll
      for (int in = 0; in < 8; in++)
        acc[im][in] = __builtin_amdgcn_mfma_f32_16x16x32_bf16(
            af[im], bf[in], acc[im][in], 0, 0, 0);
  }

  // ---- epilogue: bias + tanh; NT stores keep x resident in L2/L3
#pragma unroll
  for (int in = 0; in < 8; in++) {
    int n = nBase + in * 16 + rid;
    float bias = bc[n];
#pragma unroll
    for (int im = 0; im < 2; im++) {
      int mrow = rowBase + im * 16 + kgrp * 4;
#pragma unroll
      for (int r = 0; r < 4; r++) {
        int m = mrow + r;
        float v = acc[im][in][r] + bias;
        // tanh(v) = 1 - 2/(exp(2v)+1); overflow -> 1, underflow -> -1
        float t = 1.f - 2.f / (__expf(2.f * v) + 1.f);
        __builtin_nontemporal_store(t, &out[(size_t)m * Hn + n]);
        if ((m & (Tn - 1)) == (Tn - 1))
          out[(size_t)Mn * Hn + (size_t)(m >> 12) * Hn + n] = t;
      }
    }
  }
}

extern "C" void kernel_launch(void* const* d_in, const int* in_sizes, int n_in,
                              void* d_out, int out_size, void* d_ws,
                              size_t ws_size, hipStream_t stream) {
  (void)in_sizes; (void)n_in; (void)out_size; (void)ws_size;
  const float* x  = (const float*)d_in[0];
  const float* Wi = (const float*)d_in[1];
  const float* bi = (const float*)d_in[2];
  const float* Wh = (const float*)d_in[3];
  const float* bh = (const float*)d_in[4];
  float* out = (float*)d_out;

  unsigned short* Wc = (unsigned short*)d_ws; // 128 KB bf16 folded W
  float* bc = (float*)((char*)d_ws + (size_t)Hn * Cn * sizeof(unsigned short));

  prep_kernel<<<(Hn * Cn) / 256, 256, 0, stream>>>(Wi, bi, Wh, bh, Wc, bc);
  // 1024 blocks: 512 m-blocks x 2 n-halves; mb = bid&511 so both n-halves
  // of an m-block share an XCD (blockIdx%8 XCD heuristic, 512%8==0).
  gemm_tanh_kernel<<<1024, 256, 0, stream>>>(x, Wc, bc, out);
}

// Round 4
// 135.333 us; speedup vs baseline: 1.0563x; 1.0039x over previous
//
#include <hip/hip_runtime.h>

// hidden = tanh(x @ (Wi+Wh)^T + (bi+bh)); h_last = hidden[:, -1, :]
// GEMM M=65536 N=256 K=256 fp32 in/out, bf16 MFMA. ~134 MB traffic floor.
// R4: 512-thr blocks (8 waves), wave = 16 rows x 128 cols. acc=32 VGPR,
// full-K A-slab = 64 VGPR -> ~116 total under the (512,4) 128-reg cap, so
// the WHOLE slab stays in flight. 16 waves/CU (2 blocks x 8; LDS 64KB x2).
// One barrier total; regular stores (NT hurt write efficiency in R3).

using short8 = __attribute__((ext_vector_type(8))) short;
using f32x4  = __attribute__((ext_vector_type(4))) float;

constexpr int Tn = 4096, Cn = 256, Hn = 256;
constexpr int Mn = 16 * Tn; // 65536

// round-to-nearest-even fp32 -> bf16, two packed into one u32
__device__ inline unsigned pack2_bf16(float a, float b) {
  unsigned ua = __float_as_uint(a);
  unsigned ub = __float_as_uint(b);
  ua += 0x7fffu + ((ua >> 16) & 1u);
  ub += 0x7fffu + ((ub >> 16) & 1u);
  return (ua >> 16) | (ub & 0xffff0000u);
}

union u4s8 { uint4 u; short8 s; };

__global__ __launch_bounds__(256) void prep_kernel(
    const float* __restrict__ Wi, const float* __restrict__ bi,
    const float* __restrict__ Wh, const float* __restrict__ bh,
    unsigned short* __restrict__ Wc, float* __restrict__ bc) {
  int idx = blockIdx.x * 256 + threadIdx.x;
  float w = Wi[idx] + Wh[idx];
  unsigned u = __float_as_uint(w);
  u += 0x7fffu + ((u >> 16) & 1u);
  Wc[idx] = (unsigned short)(u >> 16);
  if (blockIdx.x == 0) bc[threadIdx.x] = bi[threadIdx.x] + bh[threadIdx.x];
}

// 512 thr = 8 waves. Block tile: 128 rows x 128 cols. Wave: 16 rows x 128 cols.
__global__ __launch_bounds__(512, 4) void gemm_tanh_kernel(
    const float* __restrict__ x, const unsigned short* __restrict__ Wc,
    const float* __restrict__ bc, float* __restrict__ out) {
  // 128 n-rows x 256 k bf16; 16B-chunk XOR swizzle: chunk' = chunk ^ (row&7)
  __shared__ __align__(16) unsigned short Bsm[128 * 256]; // 64 KB

  const int tid   = threadIdx.x;
  const int bid   = blockIdx.x;
  const int mb    = bid & 511;  // n-siblings of an m-block share XCD (512%8==0)
  const int nb    = bid >> 9;
  const int mBase = mb * 128;
  const int nBase = nb * 128;

  const int wave = tid >> 6;   // 0..7 -> 16-row slice
  const int lane = tid & 63;
  const int rid  = lane & 15;  // row/col within 16x16 tile
  const int kgrp = lane >> 4;  // 0..3: k-group of 8
  const int rowBase = mBase + wave * 16;

  // ---- issue the ENTIRE K=256 A-slab for this wave (16 float4/lane = 64 VGPR)
  const float* ap = x + (size_t)(rowBase + rid) * Cn + kgrp * 8;
  float4 abuf[8][2];
#pragma unroll
  for (int kc = 0; kc < 8; kc++) {
    const float4* p = (const float4*)(ap + kc * 32);
    abuf[kc][0] = p[0];
    abuf[kc][1] = p[1];
  }

  // ---- stage W half (bf16, pre-folded): 4096 16B chunks, 8/thread
#pragma unroll
  for (int i = 0; i < 8; i++) {
    int h = i * 512 + tid; // 0..4095
    int r = h >> 5;        // local n-row 0..127
    int c = h & 31;        // 16B chunk
    uint4 v = *(const uint4*)(Wc + (size_t)(nBase + r) * Cn + c * 8);
    int pc = c ^ (r & 7);
    *(uint4*)&Bsm[(r << 8) + (pc << 3)] = v;
  }
  __syncthreads(); // the only barrier

  f32x4 acc[8];
#pragma unroll
  for (int in = 0; in < 8; in++) acc[in] = (f32x4)0.f;

#pragma unroll
  for (int kc = 0; kc < 8; kc++) {
    u4s8 t0;
    t0.u.x = pack2_bf16(abuf[kc][0].x, abuf[kc][0].y);
    t0.u.y = pack2_bf16(abuf[kc][0].z, abuf[kc][0].w);
    t0.u.z = pack2_bf16(abuf[kc][1].x, abuf[kc][1].y);
    t0.u.w = pack2_bf16(abuf[kc][1].z, abuf[kc][1].w);
    short8 af = t0.s;

    const int cbase = (kc << 2) | kgrp;
#pragma unroll
    for (int in = 0; in < 8; in++) {
      int ln = in * 16 + rid;
      short8 bf = *(const short8*)&Bsm[(ln << 8) + ((cbase ^ (ln & 7)) << 3)];
      acc[in] = __builtin_amdgcn_mfma_f32_16x16x32_bf16(af, bf, acc[in], 0, 0, 0);
    }
  }

  // ---- epilogue: bias + tanh, regular stores (L2 write-combines)
#pragma unroll
  for (int in = 0; in < 8; in++) {
    int n = nBase + in * 16 + rid;
    float bias = bc[n];
    int mrow = rowBase + kgrp * 4;
#pragma unroll
    for (int r = 0; r < 4; r++) {
      int m = mrow + r;
      float v = acc[in][r] + bias;
      // tanh(v) = 1 - 2/(exp(2v)+1); overflow -> 1, underflow -> -1
      float t = 1.f - 2.f / (__expf(2.f * v) + 1.f);
      out[(size_t)m * Hn + n] = t;
      if ((m & (Tn - 1)) == (Tn - 1))
        out[(size_t)Mn * Hn + (size_t)(m >> 12) * Hn + n] = t;
    }
  }
}

extern "C" void kernel_launch(void* const* d_in, const int* in_sizes, int n_in,
                              void* d_out, int out_size, void* d_ws,
                              size_t ws_size, hipStream_t stream) {
  (void)in_sizes; (void)n_in; (void)out_size; (void)ws_size;
  const float* x  = (const float*)d_in[0];
  const float* Wi = (const float*)d_in[1];
  const float* bi = (const float*)d_in[2];
  const float* Wh = (const float*)d_in[3];
  const float* bh = (const float*)d_in[4];
  float* out = (float*)d_out;

  unsigned short* Wc = (unsigned short*)d_ws; // 128 KB bf16 folded W
  float* bc = (float*)((char*)d_ws + (size_t)Hn * Cn * sizeof(unsigned short));

  prep_kernel<<<(Hn * Cn) / 256, 256, 0, stream>>>(Wi, bi, Wh, bh, Wc, bc);
  // 1024 blocks: 512 m-blocks x 2 n-halves; both n-halves of an m-block land
  // on the same XCD (blockIdx%8 heuristic, 512%8==0) for x L2 reuse.
  gemm_tanh_kernel<<<1024, 512, 0, stream>>>(x, Wc, bc, out);
}